// Round 6
// baseline (380.861 us; speedup 1.0000x reference)
//
#include <hip/hip_runtime.h>

typedef _Float16 f16;
typedef f16  f16x2  __attribute__((ext_vector_type(2)));
typedef f16  f16x8  __attribute__((ext_vector_type(8)));
typedef __fp16 h16x2 __attribute__((ext_vector_type(2)));
typedef float f32x16 __attribute__((ext_vector_type(16)));

#define B_   512
#define N_   2048
#define PADV -10000.0f

union F16x8 { f16x8 v; f16x2 h2[4]; };

__device__ __forceinline__ f16x2 pkrtz(float a, float b) {
    h16x2 r = __builtin_amdgcn_cvt_pkrtz(a, b);
    return __builtin_bit_cast(f16x2, r);
}

// wtbuf layout (f16):
//   [0, 2048):        W0t [128 out][16 in]
//   [2048, 18432):    Wt1 [128 out][128 slot]  (slot = sigma-permuted in-ch)
//   [18432, 34816):   Wt2 same
//   [34816, 51200):   W3x frag-ordered: element ((s*4+c)*64 + lane)*8 + j =
//                     W3[in=sigma(16s+8*(lane>>5)+j)][out=32c+(lane&31)]
// sigma(slot): s2=slot>>4,q2=(slot>>3)&1,j2=slot&7 ->
//   32*(s2>>1)+16*(s2&1)+4*q2+8*(j2>>2)+(j2&3)
__global__ void prep_kernel(const float* __restrict__ w0, const float* __restrict__ w1,
                            const float* __restrict__ w2, const float* __restrict__ w3,
                            f16* __restrict__ wt, float* __restrict__ pooled,
                            int* __restrict__ cnt)
{
    int i = blockIdx.x * 256 + threadIdx.x;   // grid 256*256 = 65536
    if (i < 2048) {
        wt[i] = (f16)w0[(i & 15) * 128 + (i >> 4)];
    } else if (i < 34816) {
        int j = i - 2048;
        int l = j >> 14, r = j & 16383;
        int o = r >> 7, slot = r & 127;
        int s = slot >> 4, qq = (slot >> 3) & 1, jj = slot & 7;
        int sig = 32 * (s >> 1) + 16 * (s & 1) + 4 * qq + 8 * (jj >> 2) + (jj & 3);
        const float* w = (l == 0) ? w1 : w2;
        wt[i] = (f16)w[sig * 128 + o];
    } else if (i < 51200) {
        int k = i - 34816;           // [0, 16384)
        int jj = k & 7;
        int lane = (k >> 3) & 63;
        int sc = k >> 9;             // 0..31
        int s = sc >> 2, c = sc & 3;
        int l31 = lane & 31, qq = lane >> 5;
        int row = 32 * c + l31;
        int sig = 32 * (s >> 1) + 16 * (s & 1) + 4 * qq + 8 * (jj >> 2) + (jj & 3);
        wt[i] = (f16)w3[sig * 128 + row];
    }
    pooled[i & 65535] = 0.f;
    if (i < 512) cnt[i] = 0;
}

// swizzled byte offset into a [128 row][16 chunk] 16B-chunk weight tile
__device__ __forceinline__ int swz(int row, int chunk) {
    return row * 256 + ((chunk ^ (row & 15)) << 4);
}

__device__ __forceinline__ void gl_lds16(const void* g, void* l) {
    __builtin_amdgcn_global_load_lds(
        (const __attribute__((address_space(1))) void*)g,
        (__attribute__((address_space(3))) void*)l, 16, 0, 0);
}

// ---- fused deepset: phi (4 layers f16 MFMA) + pool + inline rho ----
// 256 blocks x 512 thr; block handles b = {2*blk, 2*blk+1}; wave wv: half=wv>>2,
// w4=wv&3; wave processes groups (w4 + 4*g), g=0..7, of 64 points each.
__global__ __launch_bounds__(512, 2) void deepset_kernel(
    const float* __restrict__ x, const f16* __restrict__ wtbuf,
    float* __restrict__ pooled, int* __restrict__ cntG,
    const float* __restrict__ pb0, const float* __restrict__ pb1,
    const float* __restrict__ pb2, const float* __restrict__ pb3,
    const float* __restrict__ rw0, const float* __restrict__ rb0,
    const float* __restrict__ rw1, const float* __restrict__ rb1,
    const float* __restrict__ rw2, const float* __restrict__ rb2,
    const float* __restrict__ rw3, const float* __restrict__ rb3,
    float* __restrict__ out)
{
    __shared__ f16 wAll[32768];   // 64 KB: W1 at byte 0, W2 at byte 32768

    const int tid  = threadIdx.x;
    const int lane = tid & 63;
    const int wv   = tid >> 6;          // 0..7
    const int l31  = lane & 31;
    const int q    = lane >> 5;
    const int half = wv >> 2;
    const int w4   = wv & 3;
    const int bb   = blockIdx.x * 2 + half;

    // ---- stage W1+W2 -> LDS (each wave 32 rows of 256) ----
    {
        const f16* wsrc = wtbuf + 2048;
        #pragma unroll
        for (int i = 0; i < 8; ++i) {
            const int row   = wv * 32 + i * 4 + (lane >> 4);   // 0..255
            const int chunk = (lane & 15) ^ (row & 15);
            const int loff  = (wv * 32 + i * 4) * 256;
            gl_lds16(wsrc + row * 128 + chunk * 8, (char*)wAll + loff);
        }
    }

    // ---- persistent frags: W0 (global, L1-hot), L3 bias ----
    f16x8 w0f[4];
    #pragma unroll
    for (int c = 0; c < 4; ++c)
        w0f[c] = *(const f16x8*)(wtbuf + (32 * c + l31) * 16 + 8 * q);
    float bL[4];
    #pragma unroll
    for (int c = 0; c < 4; ++c) bL[c] = pb3[32 * c + l31];

    const f16* w3x = wtbuf + 34816;

    // ---- prefetch group 0 x ----
    const size_t rowb = (size_t)bb * N_;
    float4 na0, na1, nc0, nc1;
    {
        const float* xg = x + (rowb + (size_t)(64 * w4 + l31)) * 16 + 8 * q;
        na0 = ((const float4*)xg)[0];
        na1 = ((const float4*)xg)[1];
        nc0 = ((const float4*)(xg + 512))[0];
        nc1 = ((const float4*)(xg + 512))[1];
    }

    float sums[4] = {0.f, 0.f, 0.f, 0.f};
    f32x16 acc[2][4];
    F16x8 hf[2][8];

    #define INIT_ACC_BIAS(pb)                                              \
        {                                                                  \
            _Pragma("unroll")                                              \
            for (int c = 0; c < 4; ++c) {                                  \
                _Pragma("unroll")                                          \
                for (int g2 = 0; g2 < 4; ++g2) {                           \
                    float4 bbv = *(const float4*)((pb) + 32 * c + 8 * g2 + 4 * q); \
                    const float* bbp = (const float*)&bbv;                 \
                    _Pragma("unroll")                                      \
                    for (int e = 0; e < 4; ++e) {                          \
                        acc[0][c][4 * g2 + e] = bbp[e];                    \
                        acc[1][c][4 * g2 + e] = bbp[e];                    \
                    }                                                      \
                }                                                          \
            }                                                              \
        }

    #define EPILOGUE()                                                     \
        {                                                                  \
            const f16x2 z2 = {(f16)0.f, (f16)0.f};                         \
            _Pragma("unroll")                                              \
            for (int t = 0; t < 2; ++t) {                                  \
                _Pragma("unroll")                                          \
                for (int s = 0; s < 8; ++s) {                              \
                    const int c = s >> 1, r0 = 8 * (s & 1);                \
                    _Pragma("unroll")                                      \
                    for (int p = 0; p < 4; ++p) {                          \
                        f16x2 m = pkrtz(                                   \
                            acc[t][c][r0 + 2 * p], acc[t][c][r0 + 2 * p + 1]); \
                        hf[t][s].h2[p] = __builtin_elementwise_max(m, z2); \
                    }                                                      \
                }                                                          \
            }                                                              \
        }

    __syncthreads();   // staging drained

    #pragma unroll 1
    for (int g = 0; g < 8; ++g) {
        const float4 a0 = na0, a1 = na1, c0 = nc0, c1 = nc1;

        // row validity (pad is a suffix; rows after first pad are masked by ref)
        bool vA = (a0.x != PADV) || (a0.y != PADV) || (a0.z != PADV) || (a0.w != PADV) ||
                  (a1.x != PADV) || (a1.y != PADV) || (a1.z != PADV) || (a1.w != PADV);
        bool vB = (c0.x != PADV) || (c0.y != PADV) || (c0.z != PADV) || (c0.w != PADV) ||
                  (c1.x != PADV) || (c1.y != PADV) || (c1.z != PADV) || (c1.w != PADV);
        unsigned long long blA = __ballot(vA), blB = __ballot(vB);
        const unsigned mA = (unsigned)blA | (unsigned)(blA >> 32);
        const unsigned mB = (unsigned)blB | (unsigned)(blB >> 32);
        if ((mA | mB) == 0u) break;   // suffix => all later groups dead too

        // layer-0 B-frags
        hf[0][0].h2[0] = pkrtz(a0.x, a0.y);
        hf[0][0].h2[1] = pkrtz(a0.z, a0.w);
        hf[0][0].h2[2] = pkrtz(a1.x, a1.y);
        hf[0][0].h2[3] = pkrtz(a1.z, a1.w);
        hf[1][0].h2[0] = pkrtz(c0.x, c0.y);
        hf[1][0].h2[1] = pkrtz(c0.z, c0.w);
        hf[1][0].h2[2] = pkrtz(c1.x, c1.y);
        hf[1][0].h2[3] = pkrtz(c1.z, c1.w);

        // prefetch next group's x (overwrites na*, already consumed)
        {
            const int gn = (g < 7) ? g + 1 : 7;
            const float* xg = x + (rowb + (size_t)(64 * (w4 + 4 * gn) + l31)) * 16 + 8 * q;
            na0 = ((const float4*)xg)[0];
            na1 = ((const float4*)xg)[1];
            nc0 = ((const float4*)(xg + 512))[0];
            nc1 = ((const float4*)(xg + 512))[1];
        }

        // ---- L0 ----
        INIT_ACC_BIAS(pb0);
        #pragma unroll
        for (int c = 0; c < 4; ++c) {
            acc[0][c] = __builtin_amdgcn_mfma_f32_32x32x16_f16(w0f[c], hf[0][0].v, acc[0][c], 0, 0, 0);
            acc[1][c] = __builtin_amdgcn_mfma_f32_32x32x16_f16(w0f[c], hf[1][0].v, acc[1][c], 0, 0, 0);
        }
        EPILOGUE();

        // ---- L1 (LDS bytes [0,32768)) ----
        INIT_ACC_BIAS(pb1);
        #pragma unroll
        for (int s = 0; s < 8; ++s) {
            f16x8 wf[4];
            #pragma unroll
            for (int c = 0; c < 4; ++c)
                wf[c] = *(const f16x8*)((const char*)wAll + swz(32 * c + l31, 2 * s + q));
            #pragma unroll
            for (int c = 0; c < 4; ++c) {
                acc[0][c] = __builtin_amdgcn_mfma_f32_32x32x16_f16(wf[c], hf[0][s].v, acc[0][c], 0, 0, 0);
                acc[1][c] = __builtin_amdgcn_mfma_f32_32x32x16_f16(wf[c], hf[1][s].v, acc[1][c], 0, 0, 0);
            }
        }
        EPILOGUE();

        // ---- L2 (LDS bytes [32768,65536)) ----
        INIT_ACC_BIAS(pb2);
        #pragma unroll
        for (int s = 0; s < 8; ++s) {
            f16x8 wf[4];
            #pragma unroll
            for (int c = 0; c < 4; ++c)
                wf[c] = *(const f16x8*)((const char*)wAll + 32768 + swz(32 * c + l31, 2 * s + q));
            #pragma unroll
            for (int c = 0; c < 4; ++c) {
                acc[0][c] = __builtin_amdgcn_mfma_f32_32x32x16_f16(wf[c], hf[0][s].v, acc[0][c], 0, 0, 0);
                acc[1][c] = __builtin_amdgcn_mfma_f32_32x32x16_f16(wf[c], hf[1][s].v, acc[1][c], 0, 0, 0);
            }
        }
        EPILOGUE();

        // ---- L3 swapped (W3x from global, lane-contiguous -> coalesced, L1-hot) ----
        #pragma unroll
        for (int t = 0; t < 2; ++t)
            #pragma unroll
            for (int c = 0; c < 4; ++c)
                #pragma unroll
                for (int r = 0; r < 16; ++r) acc[t][c][r] = bL[c];
        #pragma unroll
        for (int s = 0; s < 8; ++s) {
            f16x8 wf[4];
            #pragma unroll
            for (int c = 0; c < 4; ++c)
                wf[c] = *(const f16x8*)(w3x + ((s * 4 + c) * 64 + lane) * 8);
            #pragma unroll
            for (int c = 0; c < 4; ++c) {
                acc[0][c] = __builtin_amdgcn_mfma_f32_32x32x16_f16(hf[0][s].v, wf[c], acc[0][c], 0, 0, 0);
                acc[1][c] = __builtin_amdgcn_mfma_f32_32x32x16_f16(hf[1][s].v, wf[c], acc[1][c], 0, 0, 0);
            }
        }

        // ---- pool accumulate (masked select, NaN-safe) ----
        #pragma unroll
        for (int c = 0; c < 4; ++c) {
            float s0 = 0.f;
            #pragma unroll
            for (int t = 0; t < 2; ++t) {
                const unsigned m = t ? mB : mA;
                #pragma unroll
                for (int r = 0; r < 16; ++r) {
                    const int ptl = 4 * q + (r & 3) + 8 * (r >> 2);
                    float v = fmaxf(acc[t][c][r], 0.f);
                    s0 += ((m >> ptl) & 1u) ? v : 0.f;
                }
            }
            sums[c] += s0;
        }
    }

    // ---- wave pool -> global atomics ----
    #pragma unroll
    for (int c = 0; c < 4; ++c) {
        float s0 = sums[c];
        s0 += __shfl_xor(s0, 32);
        if (q == 0) atomicAdd(&pooled[bb * 128 + 32 * c + l31], s0);
    }
    __threadfence();

    // ---- last-arriving wave of bb runs rho inline ----
    int old = 0;
    if (lane == 0) old = atomicAdd(&cntG[bb], 1);
    old = __shfl(old, 0);
    if (old == 3) {
        __threadfence();
        // coherent read-back of pooled (atomic add of 0 returns current value)
        float p0 = atomicAdd(&pooled[bb * 128 + lane], 0.f);
        float p1 = atomicAdd(&pooled[bb * 128 + 64 + lane], 0.f);
        const float* rws[3] = {rw0, rw1, rw2};
        const float* rbs[3] = {rb0, rb1, rb2};
        #pragma unroll 1
        for (int l = 0; l < 3; ++l) {
            const float* w = rws[l];
            float acc0 = rbs[l][lane];
            float acc1 = rbs[l][64 + lane];
            #pragma unroll 8
            for (int k = 0; k < 64; ++k) {
                float pk = __shfl(p0, k);
                acc0 = fmaf(pk, w[k * 128 + lane], acc0);
                acc1 = fmaf(pk, w[k * 128 + 64 + lane], acc1);
            }
            #pragma unroll 8
            for (int k = 0; k < 64; ++k) {
                float pk = __shfl(p1, k);
                acc0 = fmaf(pk, w[(k + 64) * 128 + lane], acc0);
                acc1 = fmaf(pk, w[(k + 64) * 128 + 64 + lane], acc1);
            }
            p0 = fmaxf(acc0, 0.f);
            p1 = fmaxf(acc1, 0.f);
        }
        float v = p0 * rw3[lane] + p1 * rw3[64 + lane];
        #pragma unroll
        for (int off = 32; off > 0; off >>= 1)
            v += __shfl_down(v, off, 64);
        if (lane == 0) out[bb] = v + rb3[0];
    }
}

extern "C" void kernel_launch(void* const* d_in, const int* in_sizes, int n_in,
                              void* d_out, int out_size, void* d_ws, size_t ws_size,
                              hipStream_t stream)
{
    (void)in_sizes; (void)n_in; (void)out_size; (void)ws_size;
    const float* x      = (const float*)d_in[0];
    const float* phi_w0 = (const float*)d_in[1];
    const float* phi_b0 = (const float*)d_in[2];
    const float* phi_w1 = (const float*)d_in[3];
    const float* phi_b1 = (const float*)d_in[4];
    const float* phi_w2 = (const float*)d_in[5];
    const float* phi_b2 = (const float*)d_in[6];
    const float* phi_w3 = (const float*)d_in[7];
    const float* phi_b3 = (const float*)d_in[8];
    const float* rho_w0 = (const float*)d_in[9];
    const float* rho_b0 = (const float*)d_in[10];
    const float* rho_w1 = (const float*)d_in[11];
    const float* rho_b1 = (const float*)d_in[12];
    const float* rho_w2 = (const float*)d_in[13];
    const float* rho_b2 = (const float*)d_in[14];
    const float* rho_w3 = (const float*)d_in[15];
    const float* rho_b3 = (const float*)d_in[16];

    float* pooled = (float*)d_ws;                              // 65536 f32 = 262144 B
    int*   cntG   = (int*)((char*)d_ws + 262144);              // 512 i32  = 2048 B
    f16*   wtbuf  = (f16*)((char*)d_ws + 262144 + 2048);       // 51200 f16

    prep_kernel<<<256, 256, 0, stream>>>(phi_w0, phi_w1, phi_w2, phi_w3,
                                         wtbuf, pooled, cntG);
    deepset_kernel<<<256, 512, 0, stream>>>(x, wtbuf, pooled, cntG,
                                            phi_b0, phi_b1, phi_b2, phi_b3,
                                            rho_w0, rho_b0, rho_w1, rho_b1,
                                            rho_w2, rho_b2, rho_w3, rho_b3,
                                            (float*)d_out);
}

// Round 7
// 379.966 us; speedup vs baseline: 1.0024x; 1.0024x over previous
//
#include <hip/hip_runtime.h>

typedef _Float16 f16;
typedef f16  f16x2  __attribute__((ext_vector_type(2)));
typedef f16  f16x8  __attribute__((ext_vector_type(8)));
typedef __fp16 h16x2 __attribute__((ext_vector_type(2)));
typedef float f32x16 __attribute__((ext_vector_type(16)));

#define B_   512
#define N_   2048
#define PADV -10000.0f

union F16x8 { f16x8 v; f16x2 h2[4]; };

__device__ __forceinline__ f16x2 pkrtz(float a, float b) {
    h16x2 r = __builtin_amdgcn_cvt_pkrtz(a, b);
    return __builtin_bit_cast(f16x2, r);
}

// wtbuf layout (f16):
//   [0, 2048):        W0t [128 out][16 in]
//   [2048, 18432):    Wt1 [128 out][128 slot]  (slot = sigma-permuted in-ch)
//   [18432, 34816):   Wt2 same
//   [34816, 51200):   W3x frag-ordered, element ((s*4+c)*64 + lane)*8 + j =
//                     W3[in=sigma-ordered][out=32c+(lane&31)]  (R6-verified)
// sigma(slot): s2=slot>>4,q2=(slot>>3)&1,j2=slot&7 ->
//   32*(s2>>1)+16*(s2&1)+4*q2+8*(j2>>2)+(j2&3)
__global__ void prep_kernel(const float* __restrict__ w0, const float* __restrict__ w1,
                            const float* __restrict__ w2, const float* __restrict__ w3,
                            f16* __restrict__ wt, float* __restrict__ pooled,
                            int* __restrict__ qhead)
{
    int i = blockIdx.x * 256 + threadIdx.x;   // grid 256*256 = 65536
    if (i < 2048) {
        wt[i] = (f16)w0[(i & 15) * 128 + (i >> 4)];
    } else if (i < 34816) {
        int j = i - 2048;
        int l = j >> 14, r = j & 16383;
        int o = r >> 7, slot = r & 127;
        int s = slot >> 4, qq = (slot >> 3) & 1, jj = slot & 7;
        int sig = 32 * (s >> 1) + 16 * (s & 1) + 4 * qq + 8 * (jj >> 2) + (jj & 3);
        const float* w = (l == 0) ? w1 : w2;
        wt[i] = (f16)w[sig * 128 + o];
    } else if (i < 51200) {
        int k = i - 34816;           // [0, 16384)
        int jj = k & 7;
        int lane = (k >> 3) & 63;
        int sc = k >> 9;             // 0..31
        int s = sc >> 2, c = sc & 3;
        int l31 = lane & 31, qq = lane >> 5;
        int row = 32 * c + l31;
        int sig = 32 * (s >> 1) + 16 * (s & 1) + 4 * qq + 8 * (jj >> 2) + (jj & 3);
        wt[i] = (f16)w3[sig * 128 + row];
    }
    pooled[i] = 0.f;                 // 512*128 = 65536
    if (i == 0) *qhead = 0;
}

// swizzled byte offset into a [128 row][16 chunk] 16B-chunk weight tile
__device__ __forceinline__ int swz(int row, int chunk) {
    return row * 256 + ((chunk ^ (row & 15)) << 4);
}

__device__ __forceinline__ void gl_lds16(const void* g, void* l) {
    __builtin_amdgcn_global_load_lds(
        (const __attribute__((address_space(1))) void*)g,
        (__attribute__((address_space(3))) void*)l, 16, 0, 0);
}

// ---- fused phi (4 layers, f16 MFMA) + masked pool, dynamic wave-level queue ----
// 512 persistent blocks x 256 thr (2/CU). Weights staged once; each wave grabs
// 64-pt units (b = u>>5, group = u&31) from qhead until exhausted.
__global__ __launch_bounds__(256, 2) void phi_pool_kernel(
    const float* __restrict__ x,
    const f16*  __restrict__ wtbuf,
    float* __restrict__ pooled, int* __restrict__ qhead,
    const float* __restrict__ pb0, const float* __restrict__ pb1,
    const float* __restrict__ pb2, const float* __restrict__ pb3)
{
    __shared__ f16 wA[16384];   // 32 KB swizzled W1
    __shared__ f16 wB[16384];   // 32 KB swizzled W2

    const int tid  = threadIdx.x;
    const int lane = tid & 63;
    const int wv   = tid >> 6;          // 4 waves
    const int l31  = lane & 31;
    const int q    = lane >> 5;

    // ---- stage W1 -> wA, W2 -> wB once (each wave rows [32wv, 32wv+32)) ----
    {
        const f16* wl1 = wtbuf + 2048;
        const f16* wl2 = wtbuf + 2048 + 16384;
        #pragma unroll
        for (int i = 0; i < 8; ++i) {
            const int row   = wv * 32 + i * 4 + (lane >> 4);
            const int chunk = (lane & 15) ^ (row & 15);
            const int loff  = (wv * 32 + i * 4) * 256;   // bytes, wave-uniform
            gl_lds16(wl1 + row * 128 + chunk * 8, (char*)wA + loff);
            gl_lds16(wl2 + row * 128 + chunk * 8, (char*)wB + loff);
        }
    }

    // ---- persistent frags: W0 (L2-hot), L3 bias ----
    f16x8 w0f[4];
    #pragma unroll
    for (int c = 0; c < 4; ++c)
        w0f[c] = *(const f16x8*)(wtbuf + (32 * c + l31) * 16 + 8 * q);
    float bL[4];
    #pragma unroll
    for (int c = 0; c < 4; ++c) bL[c] = pb3[32 * c + l31];
    const f16* w3x = wtbuf + 34816;

    __syncthreads();   // staging drained

    // ---- first grab + x load ----
    int j;
    if (lane == 0) j = atomicAdd(qhead, 1);
    j = __shfl(j, 0);
    bool have = (j < 16384);
    float4 a0, a1, c0, c1;
    if (have) {
        const float* xg = x + ((size_t)(j >> 5) * N_ + (size_t)((j & 31) * 64 + l31)) * 16 + 8 * q;
        a0 = ((const float4*)xg)[0];
        a1 = ((const float4*)xg)[1];
        c0 = ((const float4*)(xg + 512))[0];
        c1 = ((const float4*)(xg + 512))[1];
    }

    f32x16 acc[2][4];
    F16x8 hf[2][8];

    #define INIT_ACC_BIAS(pb)                                              \
        {                                                                  \
            _Pragma("unroll")                                              \
            for (int c = 0; c < 4; ++c) {                                  \
                _Pragma("unroll")                                          \
                for (int g2 = 0; g2 < 4; ++g2) {                           \
                    float4 bbv = *(const float4*)((pb) + 32 * c + 8 * g2 + 4 * q); \
                    const float* bbp = (const float*)&bbv;                 \
                    _Pragma("unroll")                                      \
                    for (int e = 0; e < 4; ++e) {                          \
                        acc[0][c][4 * g2 + e] = bbp[e];                    \
                        acc[1][c][4 * g2 + e] = bbp[e];                    \
                    }                                                      \
                }                                                          \
            }                                                              \
        }

    #define EPILOGUE()                                                     \
        {                                                                  \
            const f16x2 z2 = {(f16)0.f, (f16)0.f};                         \
            _Pragma("unroll")                                              \
            for (int t = 0; t < 2; ++t) {                                  \
                _Pragma("unroll")                                          \
                for (int s = 0; s < 8; ++s) {                              \
                    const int c = s >> 1, r0 = 8 * (s & 1);                \
                    _Pragma("unroll")                                      \
                    for (int p = 0; p < 4; ++p) {                          \
                        f16x2 m = pkrtz(                                   \
                            acc[t][c][r0 + 2 * p], acc[t][c][r0 + 2 * p + 1]); \
                        hf[t][s].h2[p] = __builtin_elementwise_max(m, z2); \
                    }                                                      \
                }                                                          \
            }                                                              \
        }

    #pragma unroll 1
    while (have) {
        const int bcur = j >> 5;

        // row validity from current x regs
        bool vA = (a0.x != PADV) || (a0.y != PADV) || (a0.z != PADV) || (a0.w != PADV) ||
                  (a1.x != PADV) || (a1.y != PADV) || (a1.z != PADV) || (a1.w != PADV);
        bool vB = (c0.x != PADV) || (c0.y != PADV) || (c0.z != PADV) || (c0.w != PADV) ||
                  (c1.x != PADV) || (c1.y != PADV) || (c1.z != PADV) || (c1.w != PADV);
        unsigned long long blA = __ballot(vA), blB = __ballot(vB);
        const unsigned mA = (unsigned)blA | (unsigned)(blA >> 32);
        const unsigned mB = (unsigned)blB | (unsigned)(blB >> 32);
        const bool live = (mA | mB) != 0u;

        // layer-0 B-frags (consume a0..c1)
        hf[0][0].h2[0] = pkrtz(a0.x, a0.y);
        hf[0][0].h2[1] = pkrtz(a0.z, a0.w);
        hf[0][0].h2[2] = pkrtz(a1.x, a1.y);
        hf[0][0].h2[3] = pkrtz(a1.z, a1.w);
        hf[1][0].h2[0] = pkrtz(c0.x, c0.y);
        hf[1][0].h2[1] = pkrtz(c0.z, c0.w);
        hf[1][0].h2[2] = pkrtz(c1.x, c1.y);
        hf[1][0].h2[3] = pkrtz(c1.z, c1.w);

        // grab next unit + prefetch its x into the now-dead a0..c1 regs
        if (lane == 0) j = atomicAdd(qhead, 1);
        j = __shfl(j, 0);
        const bool haveN = (j < 16384);
        if (haveN) {
            const float* xg = x + ((size_t)(j >> 5) * N_ + (size_t)((j & 31) * 64 + l31)) * 16 + 8 * q;
            a0 = ((const float4*)xg)[0];
            a1 = ((const float4*)xg)[1];
            c0 = ((const float4*)(xg + 512))[0];
            c1 = ((const float4*)(xg + 512))[1];
        }

        if (live) {
            // ---- L0 ----
            INIT_ACC_BIAS(pb0);
            #pragma unroll
            for (int c = 0; c < 4; ++c) {
                acc[0][c] = __builtin_amdgcn_mfma_f32_32x32x16_f16(w0f[c], hf[0][0].v, acc[0][c], 0, 0, 0);
                acc[1][c] = __builtin_amdgcn_mfma_f32_32x32x16_f16(w0f[c], hf[1][0].v, acc[1][c], 0, 0, 0);
            }
            EPILOGUE();

            // ---- L1 (wA) ----
            INIT_ACC_BIAS(pb1);
            #pragma unroll
            for (int s = 0; s < 8; ++s) {
                f16x8 wf[4];
                #pragma unroll
                for (int c = 0; c < 4; ++c)
                    wf[c] = *(const f16x8*)((const char*)wA + swz(32 * c + l31, 2 * s + q));
                #pragma unroll
                for (int c = 0; c < 4; ++c) {
                    acc[0][c] = __builtin_amdgcn_mfma_f32_32x32x16_f16(wf[c], hf[0][s].v, acc[0][c], 0, 0, 0);
                    acc[1][c] = __builtin_amdgcn_mfma_f32_32x32x16_f16(wf[c], hf[1][s].v, acc[1][c], 0, 0, 0);
                }
            }
            EPILOGUE();

            // ---- L2 (wB) ----
            INIT_ACC_BIAS(pb2);
            #pragma unroll
            for (int s = 0; s < 8; ++s) {
                f16x8 wf[4];
                #pragma unroll
                for (int c = 0; c < 4; ++c)
                    wf[c] = *(const f16x8*)((const char*)wB + swz(32 * c + l31, 2 * s + q));
                #pragma unroll
                for (int c = 0; c < 4; ++c) {
                    acc[0][c] = __builtin_amdgcn_mfma_f32_32x32x16_f16(wf[c], hf[0][s].v, acc[0][c], 0, 0, 0);
                    acc[1][c] = __builtin_amdgcn_mfma_f32_32x32x16_f16(wf[c], hf[1][s].v, acc[1][c], 0, 0, 0);
                }
            }
            EPILOGUE();

            // ---- L3 swapped orientation; W3x global lane-contiguous (L1/L2-hot) ----
            #pragma unroll
            for (int t = 0; t < 2; ++t)
                #pragma unroll
                for (int c = 0; c < 4; ++c)
                    #pragma unroll
                    for (int r = 0; r < 16; ++r) acc[t][c][r] = bL[c];
            #pragma unroll
            for (int s = 0; s < 8; ++s) {
                f16x8 wf[4];
                #pragma unroll
                for (int c = 0; c < 4; ++c)
                    wf[c] = *(const f16x8*)(w3x + ((s * 4 + c) * 64 + lane) * 8);
                #pragma unroll
                for (int c = 0; c < 4; ++c) {
                    acc[0][c] = __builtin_amdgcn_mfma_f32_32x32x16_f16(hf[0][s].v, wf[c], acc[0][c], 0, 0, 0);
                    acc[1][c] = __builtin_amdgcn_mfma_f32_32x32x16_f16(hf[1][s].v, wf[c], acc[1][c], 0, 0, 0);
                }
            }

            // ---- pool (masked select, NaN-safe) ----
            #pragma unroll
            for (int c = 0; c < 4; ++c) {
                float s0 = 0.f;
                #pragma unroll
                for (int t = 0; t < 2; ++t) {
                    const unsigned m = t ? mB : mA;
                    #pragma unroll
                    for (int r = 0; r < 16; ++r) {
                        const int ptl = 4 * q + (r & 3) + 8 * (r >> 2);
                        float v = fmaxf(acc[t][c][r], 0.f);
                        s0 += ((m >> ptl) & 1u) ? v : 0.f;
                    }
                }
                s0 += __shfl_xor(s0, 32);
                if (q == 0) atomicAdd(&pooled[bcur * 128 + 32 * c + l31], s0);
            }
        }

        have = haveN;
    }
}

// ---- rho: fp32 MLP on pooled [512][128] -> out [512] ----
__global__ __launch_bounds__(128) void rho_kernel(
    const float* __restrict__ pooled,
    const float* __restrict__ w0, const float* __restrict__ b0,
    const float* __restrict__ w1, const float* __restrict__ b1,
    const float* __restrict__ w2, const float* __restrict__ b2,
    const float* __restrict__ w3, const float* __restrict__ b3,
    float* __restrict__ out)
{
    __shared__ float buf[2][128];
    __shared__ float red[2];
    const int b = blockIdx.x, t = threadIdx.x;
    buf[0][t] = pooled[b * 128 + t];
    __syncthreads();
    const float* ws3[3] = {w0, w1, w2};
    const float* bs3[3] = {b0, b1, b2};
    int cur = 0;
    #pragma unroll 1
    for (int l = 0; l < 3; ++l) {
        float acc = bs3[l][t];
        const float* w = ws3[l];
        #pragma unroll 8
        for (int k = 0; k < 128; ++k)
            acc = fmaf(buf[cur][k], w[k * 128 + t], acc);
        buf[cur ^ 1][t] = fmaxf(acc, 0.f);
        cur ^= 1;
        __syncthreads();
    }
    float v = buf[cur][t] * w3[t];
    #pragma unroll
    for (int off = 32; off > 0; off >>= 1)
        v += __shfl_down(v, off, 64);
    if ((t & 63) == 0) red[t >> 6] = v;
    __syncthreads();
    if (t == 0) out[b] = red[0] + red[1] + b3[0];
}

extern "C" void kernel_launch(void* const* d_in, const int* in_sizes, int n_in,
                              void* d_out, int out_size, void* d_ws, size_t ws_size,
                              hipStream_t stream)
{
    (void)in_sizes; (void)n_in; (void)out_size; (void)ws_size;
    const float* x      = (const float*)d_in[0];
    const float* phi_w0 = (const float*)d_in[1];
    const float* phi_b0 = (const float*)d_in[2];
    const float* phi_w1 = (const float*)d_in[3];
    const float* phi_b1 = (const float*)d_in[4];
    const float* phi_w2 = (const float*)d_in[5];
    const float* phi_b2 = (const float*)d_in[6];
    const float* phi_w3 = (const float*)d_in[7];
    const float* phi_b3 = (const float*)d_in[8];
    const float* rho_w0 = (const float*)d_in[9];
    const float* rho_b0 = (const float*)d_in[10];
    const float* rho_w1 = (const float*)d_in[11];
    const float* rho_b1 = (const float*)d_in[12];
    const float* rho_w2 = (const float*)d_in[13];
    const float* rho_b2 = (const float*)d_in[14];
    const float* rho_w3 = (const float*)d_in[15];
    const float* rho_b3 = (const float*)d_in[16];

    float* pooled = (float*)d_ws;                              // 65536 f32 = 262144 B
    int*   qhead  = (int*)((char*)d_ws + 262144);              // 4 B (pad to 2048)
    f16*   wtbuf  = (f16*)((char*)d_ws + 262144 + 2048);       // 51200 f16

    prep_kernel<<<256, 256, 0, stream>>>(phi_w0, phi_w1, phi_w2, phi_w3,
                                         wtbuf, pooled, qhead);
    phi_pool_kernel<<<512, 256, 0, stream>>>(x, wtbuf, pooled, qhead,
                                             phi_b0, phi_b1, phi_b2, phi_b3);
    rho_kernel<<<B_, 128, 0, stream>>>(pooled, rho_w0, rho_b0, rho_w1, rho_b1,
                                       rho_w2, rho_b2, rho_w3, rho_b3, (float*)d_out);
}

// Round 8
// 204.499 us; speedup vs baseline: 1.8624x; 1.8580x over previous
//
#include <hip/hip_runtime.h>

typedef _Float16 f16;
typedef f16  f16x2  __attribute__((ext_vector_type(2)));
typedef f16  f16x8  __attribute__((ext_vector_type(8)));
typedef __fp16 h16x2 __attribute__((ext_vector_type(2)));
typedef float f32x16 __attribute__((ext_vector_type(16)));

#define B_   512
#define N_   2048
#define PADV -10000.0f

union F16x8 { f16x8 v; f16x2 h2[4]; };

__device__ __forceinline__ f16x2 pkrtz(float a, float b) {
    h16x2 r = __builtin_amdgcn_cvt_pkrtz(a, b);
    return __builtin_bit_cast(f16x2, r);
}

// wtbuf layout (f16): W0t [128 out][16 in] at 0 (natural in-order)
// Wt1/Wt2/Wt3 [128 out][128 slot] at 2048/18432/34816, where slot k is the
// PERMUTED input-channel order sigma(slot) matching the MFMA D-register layout:
//   s=slot>>4, q=(slot>>3)&1, j=slot&7
//   sigma = 32*(s>>1) + 16*(s&1) + 4*q + 8*(j>>2) + (j&3)
__global__ void prep_kernel(const float* __restrict__ w0, const float* __restrict__ w1,
                            const float* __restrict__ w2, const float* __restrict__ w3,
                            f16* __restrict__ out, float* __restrict__ pooled)
{
    int i = blockIdx.x * 256 + threadIdx.x;   // grid 256*256 = 65536
    if (i < 2048) {
        out[i] = (f16)w0[(i & 15) * 128 + (i >> 4)];
    } else if (i < 51200) {
        int j = i - 2048;
        int l = j >> 14, r = j & 16383;
        int o = r >> 7, slot = r & 127;
        int s = slot >> 4, qq = (slot >> 3) & 1, jj = slot & 7;
        int sig = 32 * (s >> 1) + 16 * (s & 1) + 4 * qq + 8 * (jj >> 2) + (jj & 3);
        const float* w = (l == 0) ? w1 : (l == 1) ? w2 : w3;
        out[i] = (f16)w[sig * 128 + o];
    }
    pooled[i] = 0.f;   // 512*128 = 65536
}

// swizzled byte offset into a [128 row][16 chunk] 16B-chunk weight tile
__device__ __forceinline__ int swz(int row, int chunk) {
    return row * 256 + ((chunk ^ (row & 15)) << 4);
}

__device__ __forceinline__ void gl_lds16(const void* g, void* l) {
    __builtin_amdgcn_global_load_lds(
        (const __attribute__((address_space(1))) void*)g,
        (__attribute__((address_space(3))) void*)l, 16, 0, 0);
}

// ---- fused phi (4 layers, f16 MFMA, h in registers, no shuffles) + masked pool ----
// Mapping note: b = blockIdx&511, tile = blockIdx>>9. Low bits of blockIdx map to
// XCD (i%8) on MI355X; R5's tile=blockIdx&7 pinned tile position to XCD (XCD0 got
// all always-live tile-0 blocks -> no speedup from early exit). This mapping gives
// every XCD/CU a uniform tile mix so dead blocks recycle their slot dynamically.
__global__ __launch_bounds__(256, 2) void phi_pool_kernel(
    const float* __restrict__ x,
    const f16*  __restrict__ wtbuf,
    const float* __restrict__ pb0, const float* __restrict__ pb1,
    const float* __restrict__ pb2, const float* __restrict__ pb3,
    float* __restrict__ pooled)
{
    __shared__ f16 wA[16384];   // 32 KB swizzled [128 out][128 slot]
    __shared__ f16 wB[16384];

    const int tid  = threadIdx.x;
    const int lane = tid & 63;
    const int wv   = tid >> 6;          // 4 waves
    const int l31  = lane & 31;
    const int q    = lane >> 5;
    const int b    = blockIdx.x & 511;
    const int tile0 = (blockIdx.x >> 9) * 256;

    // ---- block-uniform early exit: padding is a row-suffix per b, so if the
    // tile's first row is PAD the whole 256-pt tile is PAD and pools to zero.
    {
        const float4 f0 = *(const float4*)(x + ((size_t)b * N_ + tile0) * 16);
        if (f0.x == PADV && f0.y == PADV && f0.z == PADV && f0.w == PADV) return;
    }

    const int p0 = tile0 + wv * 64;   // wave's 64-pt tile

    // ---- x loads first (oldest vmcnt), 2 rows x 8 floats per lane ----
    const float* xp = x + ((size_t)b * N_ + (size_t)(p0 + l31)) * 16 + 8 * q;
    float4 a0 = ((const float4*)xp)[0];
    float4 a1 = ((const float4*)xp)[1];
    float4 c0 = ((const float4*)(xp + 512))[0];   // +32 rows
    float4 c1 = ((const float4*)(xp + 512))[1];

    // ---- W0 A-frags from global (L2-hot) ----
    f16x8 w0f[4];
    #pragma unroll
    for (int c = 0; c < 4; ++c)
        w0f[c] = *(const f16x8*)(wtbuf + (32 * c + l31) * 16 + 8 * q);

    // ---- async stage W1 -> wA, W2 -> wB (each wave rows [32wv, 32wv+32)) ----
    {
        const f16* wl1 = wtbuf + 2048;
        const f16* wl2 = wtbuf + 2048 + 16384;
        #pragma unroll
        for (int i = 0; i < 8; ++i) {
            const int row   = wv * 32 + i * 4 + (lane >> 4);
            const int chunk = (lane & 15) ^ (row & 15);
            const int loff  = (wv * 32 + i * 4) * 256;   // bytes, wave-uniform
            gl_lds16(wl1 + row * 128 + chunk * 8, (char*)wA + loff);
            gl_lds16(wl2 + row * 128 + chunk * 8, (char*)wB + loff);
        }
    }

    // ---- validity masks (row pad iff both 8-elem halves all PAD) ----
    bool vA = (a0.x != PADV) || (a0.y != PADV) || (a0.z != PADV) || (a0.w != PADV) ||
              (a1.x != PADV) || (a1.y != PADV) || (a1.z != PADV) || (a1.w != PADV);
    bool vB = (c0.x != PADV) || (c0.y != PADV) || (c0.z != PADV) || (c0.w != PADV) ||
              (c1.x != PADV) || (c1.y != PADV) || (c1.z != PADV) || (c1.w != PADV);
    unsigned long long blA = __ballot(vA), blB = __ballot(vB);
    const unsigned mA = (unsigned)blA | (unsigned)(blA >> 32);
    const unsigned mB = (unsigned)blB | (unsigned)(blB >> 32);

    // ---- layer-0 B-frags (k = 8q+j natural order) ----
    F16x8 hf[2][8];
    hf[0][0].h2[0] = pkrtz(a0.x, a0.y);
    hf[0][0].h2[1] = pkrtz(a0.z, a0.w);
    hf[0][0].h2[2] = pkrtz(a1.x, a1.y);
    hf[0][0].h2[3] = pkrtz(a1.z, a1.w);
    hf[1][0].h2[0] = pkrtz(c0.x, c0.y);
    hf[1][0].h2[1] = pkrtz(c0.z, c0.w);
    hf[1][0].h2[2] = pkrtz(c1.x, c1.y);
    hf[1][0].h2[3] = pkrtz(c1.z, c1.w);

    f32x16 acc[2][4];

    // bias pre-load into accumulator: acc[t][c][4g+e] = bias[32c + 8g + 4q + e]
    #define INIT_ACC_BIAS(pb)                                              \
        {                                                                  \
            _Pragma("unroll")                                              \
            for (int c = 0; c < 4; ++c) {                                  \
                _Pragma("unroll")                                          \
                for (int g = 0; g < 4; ++g) {                              \
                    float4 bb = *(const float4*)((pb) + 32 * c + 8 * g + 4 * q); \
                    const float* bbp = (const float*)&bb;                  \
                    _Pragma("unroll")                                      \
                    for (int e = 0; e < 4; ++e) {                          \
                        acc[0][c][4 * g + e] = bbp[e];                     \
                        acc[1][c][4 * g + e] = bbp[e];                     \
                    }                                                      \
                }                                                          \
            }                                                              \
        }

    // epilogue: packed cvt + relu; D regs ARE the next B-frag (weights permuted)
    #define EPILOGUE()                                                     \
        {                                                                  \
            const f16x2 z2 = {(f16)0.f, (f16)0.f};                         \
            _Pragma("unroll")                                              \
            for (int t = 0; t < 2; ++t) {                                  \
                _Pragma("unroll")                                          \
                for (int s = 0; s < 8; ++s) {                              \
                    const int c = s >> 1, r0 = 8 * (s & 1);                \
                    _Pragma("unroll")                                      \
                    for (int p = 0; p < 4; ++p) {                          \
                        f16x2 m = pkrtz(                                   \
                            acc[t][c][r0 + 2 * p], acc[t][c][r0 + 2 * p + 1]); \
                        hf[t][s].h2[p] = __builtin_elementwise_max(m, z2); \
                    }                                                      \
                }                                                          \
            }                                                              \
        }

    // ---- L0: D[ch][pt], K=16 ----
    INIT_ACC_BIAS(pb0);
    #pragma unroll
    for (int c = 0; c < 4; ++c) {
        acc[0][c] = __builtin_amdgcn_mfma_f32_32x32x16_f16(w0f[c], hf[0][0].v, acc[0][c], 0, 0, 0);
        acc[1][c] = __builtin_amdgcn_mfma_f32_32x32x16_f16(w0f[c], hf[1][0].v, acc[1][c], 0, 0, 0);
    }
    EPILOGUE();

    __syncthreads();   // staging of wA/wB complete

    // ---- L1: A = W1 from wA ----
    INIT_ACC_BIAS(pb1);
    #pragma unroll
    for (int s = 0; s < 8; ++s) {
        f16x8 wf[4];
        #pragma unroll
        for (int c = 0; c < 4; ++c)
            wf[c] = *(const f16x8*)((const char*)wA + swz(32 * c + l31, 2 * s + q));
        #pragma unroll
        for (int c = 0; c < 4; ++c) {
            acc[0][c] = __builtin_amdgcn_mfma_f32_32x32x16_f16(wf[c], hf[0][s].v, acc[0][c], 0, 0, 0);
            acc[1][c] = __builtin_amdgcn_mfma_f32_32x32x16_f16(wf[c], hf[1][s].v, acc[1][c], 0, 0, 0);
        }
    }

    __syncthreads();   // all waves done reading wA

    // ---- restage W3 -> wA (overlaps L1 epilogue + L2) ----
    {
        const f16* wl3 = wtbuf + 2048 + 32768;
        #pragma unroll
        for (int i = 0; i < 8; ++i) {
            const int row   = wv * 32 + i * 4 + (lane >> 4);
            const int chunk = (lane & 15) ^ (row & 15);
            const int loff  = (wv * 32 + i * 4) * 256;
            gl_lds16(wl3 + row * 128 + chunk * 8, (char*)wA + loff);
        }
    }

    EPILOGUE();   // L1 epilogue

    // ---- L2: A = W2 from wB ----
    INIT_ACC_BIAS(pb2);
    #pragma unroll
    for (int s = 0; s < 8; ++s) {
        f16x8 wf[4];
        #pragma unroll
        for (int c = 0; c < 4; ++c)
            wf[c] = *(const f16x8*)((const char*)wB + swz(32 * c + l31, 2 * s + q));
        #pragma unroll
        for (int c = 0; c < 4; ++c) {
            acc[0][c] = __builtin_amdgcn_mfma_f32_32x32x16_f16(wf[c], hf[0][s].v, acc[0][c], 0, 0, 0);
            acc[1][c] = __builtin_amdgcn_mfma_f32_32x32x16_f16(wf[c], hf[1][s].v, acc[1][c], 0, 0, 0);
        }
    }
    EPILOGUE();   // L2 epilogue

    __syncthreads();   // W3 staging drained

    // ---- L3: swapped orientation D[pt][ch]; bias = b3 broadcast along rows ----
    {
        float bL[4];
        #pragma unroll
        for (int c = 0; c < 4; ++c) bL[c] = pb3[32 * c + l31];
        #pragma unroll
        for (int t = 0; t < 2; ++t)
            #pragma unroll
            for (int c = 0; c < 4; ++c)
                #pragma unroll
                for (int r = 0; r < 16; ++r) acc[t][c][r] = bL[c];
    }
    #pragma unroll
    for (int s = 0; s < 8; ++s) {
        f16x8 wf[4];
        #pragma unroll
        for (int c = 0; c < 4; ++c)
            wf[c] = *(const f16x8*)((const char*)wA + swz(32 * c + l31, 2 * s + q));
        #pragma unroll
        for (int c = 0; c < 4; ++c) {
            acc[0][c] = __builtin_amdgcn_mfma_f32_32x32x16_f16(hf[0][s].v, wf[c], acc[0][c], 0, 0, 0);
            acc[1][c] = __builtin_amdgcn_mfma_f32_32x32x16_f16(hf[1][s].v, wf[c], acc[1][c], 0, 0, 0);
        }
    }

    // ---- pool: lane owns ch = 32c + l31; rows are pts; masked select ----
    #pragma unroll
    for (int c = 0; c < 4; ++c) {
        float s0 = 0.f;
        #pragma unroll
        for (int t = 0; t < 2; ++t) {
            const unsigned m = t ? mB : mA;
            #pragma unroll
            for (int r = 0; r < 16; ++r) {
                const int ptl = 4 * q + (r & 3) + 8 * (r >> 2);
                float v = fmaxf(acc[t][c][r], 0.f);
                s0 += ((m >> ptl) & 1u) ? v : 0.f;   // select, NaN-safe
            }
        }
        s0 += __shfl_xor(s0, 32);
        if (q == 0) atomicAdd(&pooled[b * 128 + 32 * c + l31], s0);
    }
}

// ---- rho: fp32 MLP on pooled [512][128] -> out [512] ----
__global__ __launch_bounds__(128) void rho_kernel(
    const float* __restrict__ pooled,
    const float* __restrict__ w0, const float* __restrict__ b0,
    const float* __restrict__ w1, const float* __restrict__ b1,
    const float* __restrict__ w2, const float* __restrict__ b2,
    const float* __restrict__ w3, const float* __restrict__ b3,
    float* __restrict__ out)
{
    __shared__ float buf[2][128];
    __shared__ float red[2];
    const int b = blockIdx.x, t = threadIdx.x;
    buf[0][t] = pooled[b * 128 + t];
    __syncthreads();
    const float* ws3[3] = {w0, w1, w2};
    const float* bs3[3] = {b0, b1, b2};
    int cur = 0;
    #pragma unroll 1
    for (int l = 0; l < 3; ++l) {
        float acc = bs3[l][t];
        const float* w = ws3[l];
        #pragma unroll 8
        for (int k = 0; k < 128; ++k)
            acc = fmaf(buf[cur][k], w[k * 128 + t], acc);
        buf[cur ^ 1][t] = fmaxf(acc, 0.f);
        cur ^= 1;
        __syncthreads();
    }
    float v = buf[cur][t] * w3[t];
    #pragma unroll
    for (int off = 32; off > 0; off >>= 1)
        v += __shfl_down(v, off, 64);
    if ((t & 63) == 0) red[t >> 6] = v;
    __syncthreads();
    if (t == 0) out[b] = red[0] + red[1] + b3[0];
}

extern "C" void kernel_launch(void* const* d_in, const int* in_sizes, int n_in,
                              void* d_out, int out_size, void* d_ws, size_t ws_size,
                              hipStream_t stream)
{
    (void)in_sizes; (void)n_in; (void)out_size; (void)ws_size;
    const float* x      = (const float*)d_in[0];
    const float* phi_w0 = (const float*)d_in[1];
    const float* phi_b0 = (const float*)d_in[2];
    const float* phi_w1 = (const float*)d_in[3];
    const float* phi_b1 = (const float*)d_in[4];
    const float* phi_w2 = (const float*)d_in[5];
    const float* phi_b2 = (const float*)d_in[6];
    const float* phi_w3 = (const float*)d_in[7];
    const float* phi_b3 = (const float*)d_in[8];
    const float* rho_w0 = (const float*)d_in[9];
    const float* rho_b0 = (const float*)d_in[10];
    const float* rho_w1 = (const float*)d_in[11];
    const float* rho_b1 = (const float*)d_in[12];
    const float* rho_w2 = (const float*)d_in[13];
    const float* rho_b2 = (const float*)d_in[14];
    const float* rho_w3 = (const float*)d_in[15];
    const float* rho_b3 = (const float*)d_in[16];

    float* pooled = (float*)d_ws;                          // 512*128*4 = 262144 B
    f16*   wtbuf  = (f16*)((char*)d_ws + 262144);          // 51200 f16 = 102400 B

    prep_kernel<<<256, 256, 0, stream>>>(phi_w0, phi_w1, phi_w2, phi_w3, wtbuf, pooled);
    phi_pool_kernel<<<4096, 256, 0, stream>>>(x, wtbuf, phi_b0, phi_b1, phi_b2, phi_b3, pooled);
    rho_kernel<<<B_, 128, 0, stream>>>(pooled, rho_w0, rho_b0, rho_w1, rho_b1,
                                       rho_w2, rho_b2, rho_w3, rho_b3, (float*)d_out);
}